// Round 5
// baseline (7202.008 us; speedup 1.0000x reference)
//
#include <hip/hip_runtime.h>
#include <math.h>

// Problem dims
#define BATCH 32
#define SEQ   500
#define NQ    3000
#define EMB   256
#define HID   256
#define ROWS  (BATCH * SEQ)        // 16000
#define X_K   (2 * NQ)             // 6000

typedef short short8 __attribute__((ext_vector_type(8)));
typedef float f32x4  __attribute__((ext_vector_type(4)));

// ---------------- bf16 split helpers ----------------
// hi = truncate-to-bf16 (exact subtraction residual), lo = RNE-bf16 of residual.
// a ≈ hi + lo with relative error ~2^-17.
// Integer-domain RNE: (u + 0x7fff + lsb) >> 16. Inputs are finite; no NaN path.
__device__ __forceinline__ unsigned bf16_rne(float f) {
    unsigned u = __float_as_uint(f);
    return (u + 0x7fffu + ((u >> 16) & 1u)) >> 16;
}
__device__ __forceinline__ unsigned pack_bf16_rn(float a, float b) {
    return bf16_rne(a) | (bf16_rne(b) << 16);   // low16 = a, high16 = b
}

// LDS tile layout (per 128-row x 32-k tile, 16 KB):
//   byte(row, cg, p') = row*128 + ((cg ^ (row&7)) << 4) + (p'<<3)
// where cg = k>>2 (0..7 float4-group), p' = plane ^ ((row>>3)&1), plane 0=hi 1=lo.
// Staging writes one b128 per (row,cg); frag reads are b64.
// Bank = (slot*4 + plane*2) mod 32 (row*128 is bank-neutral): b64 reads land
// exactly 4 accesses/bank (structural min), b128 writes exactly 8/bank (min).
__device__ __forceinline__ void stage_tile(unsigned char* lbase, int row, int cg, float4 v) {
    unsigned ux = __float_as_uint(v.x), uy = __float_as_uint(v.y);
    unsigned uz = __float_as_uint(v.z), uw = __float_as_uint(v.w);
    unsigned hx = ux & 0xffff0000u, hy = uy & 0xffff0000u;
    unsigned hz = uz & 0xffff0000u, hw = uw & 0xffff0000u;
    unsigned hi01 = (hx >> 16) | hy;
    unsigned hi23 = (hz >> 16) | hw;
    unsigned lo01 = pack_bf16_rn(v.x - __uint_as_float(hx), v.y - __uint_as_float(hy));
    unsigned lo23 = pack_bf16_rn(v.z - __uint_as_float(hz), v.w - __uint_as_float(hw));
    const int slot = cg ^ (row & 7);
    const int pf   = (row >> 3) & 1;
    uint4 w = pf ? make_uint4(lo01, lo23, hi01, hi23)
                 : make_uint4(hi01, hi23, lo01, lo23);
    *reinterpret_cast<uint4*>(lbase + row * 128 + (slot << 4)) = w;
}

__device__ __forceinline__ void read_frag(const unsigned char* lbase, int row, int c,
                                          short8& hi, short8& lo) {
    const int r7 = row & 7;
    const int pf = (row >> 3) & 1;
    const unsigned char* rbase = lbase + row * 128;
    const int s0 = (((c << 1) | 0) ^ r7) << 4;
    const int s1 = (((c << 1) | 1) ^ r7) << 4;
    const int oh = pf << 3;
    const int ol = (pf ^ 1) << 3;
    uint2 h0 = *reinterpret_cast<const uint2*>(rbase + s0 + oh);
    uint2 h1 = *reinterpret_cast<const uint2*>(rbase + s1 + oh);
    uint2 l0 = *reinterpret_cast<const uint2*>(rbase + s0 + ol);
    uint2 l1 = *reinterpret_cast<const uint2*>(rbase + s1 + ol);
    hi = __builtin_bit_cast(short8, make_uint4(h0.x, h0.y, h1.x, h1.y));
    lo = __builtin_bit_cast(short8, make_uint4(l0.x, l0.y, l1.x, l1.y));
}

// ---------------- split-bf16 MFMA GEMM ----------------
// C[M,N] = A[M,K] @ B[N,K]^T (+bias[n]).  lda = ldb = K.  Batched via blockIdx.z.
// 128x128x32 tile, 256 threads = 4 waves in 2x2 grid, 4x4 frags of 16x16x32 per wave.
// fp32 accuracy via 3-term split: A≈Ah+Al, B≈Bh+Bl, C≈Ah·Bh+Ah·Bl+Al·Bh.
template<bool HASBIAS>
__global__ __launch_bounds__(256, 2)
void gemm_mfma(const float* __restrict__ A, const float* __restrict__ B,
               const float* __restrict__ bias, float* __restrict__ C,
               int M, int N, int K, int ldc,
               long long sA, long long sB, long long sC)
{
    A += (long long)blockIdx.z * sA;
    B += (long long)blockIdx.z * sB;
    C += (long long)blockIdx.z * sC;

    __shared__ __align__(16) unsigned char lds[32768];
    unsigned char* Al_ = lds;            // A tile: 16 KB
    unsigned char* Bl_ = lds + 16384;    // B tile: 16 KB

    const int tid = threadIdx.x;
    const int m0 = blockIdx.y * 128;
    const int n0 = blockIdx.x * 128;

    // staging coords: 4 rounds x (32 rows x 8 float4-groups)
    const int srow = tid >> 3;     // 0..31
    const int scg  = tid & 7;      // 0..7

    // wave / lane coords
    const int wid = tid >> 6;
    const int wm  = wid >> 1;      // 0..1 (m)
    const int wn  = wid & 1;       // 0..1 (n)
    const int lane = tid & 63;
    const int fr  = lane & 15;     // frag row (A m / B n / D col)
    const int fc  = lane >> 4;     // k-chunk (and D row-group)

    f32x4 acc[4][4];
    #pragma unroll
    for (int i = 0; i < 4; ++i)
        #pragma unroll
        for (int j = 0; j < 4; ++j)
            acc[i][j] = (f32x4){0.f, 0.f, 0.f, 0.f};

    const int ktiles = (K + 31) >> 5;
    for (int kt = 0; kt < ktiles; ++kt) {
        const int gk = (kt << 5) + scg * 4;
        // ---- stage A and B tiles (fp32 -> bf16 hi/lo in-register)
        #pragma unroll
        for (int rd = 0; rd < 4; ++rd) {
            const int row = rd * 32 + srow;
            {
                const int gm = m0 + row;
                float4 v = make_float4(0.f, 0.f, 0.f, 0.f);
                if (gm < M && gk < K)
                    v = *reinterpret_cast<const float4*>(A + (long long)gm * K + gk);
                stage_tile(Al_, row, scg, v);
            }
            {
                const int gn = n0 + row;
                float4 v = make_float4(0.f, 0.f, 0.f, 0.f);
                if (gn < N && gk < K)
                    v = *reinterpret_cast<const float4*>(B + (long long)gn * K + gk);
                stage_tile(Bl_, row, scg, v);
            }
        }
        __syncthreads();

        // ---- fragments
        short8 ah[4], al[4], bh[4], bl[4];
        #pragma unroll
        for (int mi = 0; mi < 4; ++mi)
            read_frag(Al_, wm * 64 + mi * 16 + fr, fc, ah[mi], al[mi]);
        #pragma unroll
        for (int ni = 0; ni < 4; ++ni)
            read_frag(Bl_, wn * 64 + ni * 16 + fr, fc, bh[ni], bl[ni]);

        // ---- 3-term split MFMA
        #pragma unroll
        for (int mi = 0; mi < 4; ++mi) {
            #pragma unroll
            for (int ni = 0; ni < 4; ++ni) {
                acc[mi][ni] = __builtin_amdgcn_mfma_f32_16x16x32_bf16(al[mi], bh[ni], acc[mi][ni], 0, 0, 0);
                acc[mi][ni] = __builtin_amdgcn_mfma_f32_16x16x32_bf16(ah[mi], bl[ni], acc[mi][ni], 0, 0, 0);
                acc[mi][ni] = __builtin_amdgcn_mfma_f32_16x16x32_bf16(ah[mi], bh[ni], acc[mi][ni], 0, 0, 0);
            }
        }
        __syncthreads();
    }

    // ---- epilogue: D lane mapping col = lane&15, row = (lane>>4)*4 + q  [m89]
    #pragma unroll
    for (int ni = 0; ni < 4; ++ni) {
        const int col = n0 + wn * 64 + ni * 16 + fr;
        if (col >= N) continue;
        const float bv = HASBIAS ? bias[col] : 0.f;
        #pragma unroll
        for (int mi = 0; mi < 4; ++mi) {
            #pragma unroll
            for (int q = 0; q < 4; ++q) {
                const int rw = m0 + wm * 64 + mi * 16 + fc * 4 + q;
                if (rw < M) C[(long long)rw * ldc + col] = acc[mi][ni][q] + bv;
            }
        }
    }
}

// ---------------- generic transpose: in[R,C] -> out[C,R], batched ----------------
__global__ __launch_bounds__(256)
void trans_kernel(const float* __restrict__ in, float* __restrict__ out,
                  int R, int C, long long sIn, long long sOut)
{
    in  += (long long)blockIdx.z * sIn;
    out += (long long)blockIdx.z * sOut;
    __shared__ float t[32][33];
    const int r0 = blockIdx.y * 32, c0 = blockIdx.x * 32;
    const int tx = threadIdx.x & 31, ty = threadIdx.x >> 5;   // ty 0..7
    #pragma unroll
    for (int i = 0; i < 32; i += 8) {
        const int r = r0 + ty + i, c = c0 + tx;
        t[ty + i][tx] = (r < R && c < C) ? in[(long long)r * C + c] : 0.f;
    }
    __syncthreads();
    #pragma unroll
    for (int i = 0; i < 32; i += 8) {
        const int r = r0 + tx, c = c0 + ty + i;
        if (c < C && r < R) out[(long long)c * R + r] = t[tx][ty + i];
    }
}

// ---------------- GRU: one block per (gru, batch) ----------------
__global__ __launch_bounds__(256)
void gru_kernel(const float* __restrict__ xp1, const float* __restrict__ xp2,
                const float* __restrict__ wT1, const float* __restrict__ wT2,
                const float* __restrict__ bh1, const float* __restrict__ bh2,
                float* __restrict__ out1, float* __restrict__ out2)
{
    const int g = blockIdx.x >> 5;
    const int b = blockIdx.x & 31;
    const float* xp = (g ? xp2 : xp1) + (long long)b * SEQ * 768;
    const float* wT = g ? wT2 : wT1;
    const float* bh = g ? bh2 : bh1;
    float* out      = (g ? out2 : out1) + (long long)b * SEQ * HID;

    __shared__ float h[HID];
    const int j = threadIdx.x;
    h[j] = 0.f;
    const float br = bh[j], bz = bh[HID + j], bn = bh[2 * HID + j];
    __syncthreads();

    for (int t = 0; t < SEQ; ++t) {
        const float* xrow = xp + (long long)t * 768;
        float ar = br, az = bz, an = bn;
        #pragma unroll 8
        for (int k = 0; k < HID; ++k) {
            const float hk = h[k];
            const float* wrow = wT + k * 768;
            ar = fmaf(hk, wrow[j], ar);
            az = fmaf(hk, wrow[HID + j], az);
            an = fmaf(hk, wrow[2 * HID + j], an);
        }
        const float r = 1.f / (1.f + __expf(-(xrow[j] + ar)));
        const float z = 1.f / (1.f + __expf(-(xrow[HID + j] + az)));
        const float n = tanhf(xrow[2 * HID + j] + r * an);
        const float hnew = (1.f - z) * n + z * h[j];
        out[(long long)t * HID + j] = hnew;
        __syncthreads();
        h[j] = hnew;
        __syncthreads();
    }
}

// ---------------- softmax over rows of length 500 (in place) ----------------
__global__ __launch_bounds__(256)
void softmax_kernel(float* __restrict__ s)
{
    float* p = s + (long long)blockIdx.x * SEQ;
    const int tid = threadIdx.x;
    __shared__ float red[256];

    const float v0 = (tid < SEQ) ? p[tid] : -1e30f;
    const float v1 = (tid + 256 < SEQ) ? p[tid + 256] : -1e30f;
    red[tid] = fmaxf(v0, v1);
    __syncthreads();
    for (int o = 128; o > 0; o >>= 1) {
        if (tid < o) red[tid] = fmaxf(red[tid], red[tid + o]);
        __syncthreads();
    }
    const float m = red[0];
    __syncthreads();
    const float e0 = (tid < SEQ) ? __expf(v0 - m) : 0.f;
    const float e1 = (tid + 256 < SEQ) ? __expf(v1 - m) : 0.f;
    red[tid] = e0 + e1;
    __syncthreads();
    for (int o = 128; o > 0; o >>= 1) {
        if (tid < o) red[tid] += red[tid + o];
        __syncthreads();
    }
    const float inv = 1.f / red[0];
    if (tid < SEQ) p[tid] = e0 * inv;
    if (tid + 256 < SEQ) p[tid + 256] = e1 * inv;
}

// ---------------- column sum: [32][500][256] -> [32][256] ----------------
__global__ __launch_bounds__(256)
void colsum_kernel(const float* __restrict__ x, float* __restrict__ out)
{
    const int b = blockIdx.x, hh = threadIdx.x;
    const float* p = x + (long long)b * SEQ * HID + hh;
    float s = 0.f;
    for (int t = 0; t < SEQ; ++t) s += p[t * HID];
    out[b * HID + hh] = s;
}

// ---------------- fused_h combine: ens[...,256+h] = colsum - tmp ----------------
__global__ __launch_bounds__(256)
void combine_kernel(const float* __restrict__ tmp, const float* __restrict__ cs,
                    float* __restrict__ ens)
{
    const long long r = blockIdx.x;
    const int hh = threadIdx.x;
    const int b = (int)(r / SEQ);
    ens[r * 512 + 256 + hh] = cs[b * HID + hh] - tmp[r * HID + hh];
}

// ---------------- launch ----------------
extern "C" void kernel_launch(void* const* d_in, const int* in_sizes, int n_in,
                              void* d_out, int out_size, void* d_ws, size_t ws_size,
                              hipStream_t stream)
{
    const float* x      = (const float*)d_in[0];
    const float* ques_h = (const float*)d_in[1];
    const float* ques_d = (const float*)d_in[2];
    const float* w1ih   = (const float*)d_in[3];
    const float* w1hh   = (const float*)d_in[4];
    const float* b1ih   = (const float*)d_in[5];
    const float* b1hh   = (const float*)d_in[6];
    const float* w2ih   = (const float*)d_in[7];
    const float* w2hh   = (const float*)d_in[8];
    const float* b2ih   = (const float*)d_in[9];
    const float* b2hh   = (const float*)d_in[10];
    const float* fcc_w  = (const float*)d_in[11];
    const float* fcc_b  = (const float*)d_in[12];
    const float* fct_w  = (const float*)d_in[13];
    const float* fct_b  = (const float*)d_in[14];
    const float* fce_w  = (const float*)d_in[15];
    const float* fce_b  = (const float*)d_in[16];

    float* ws = (float*)d_ws;
    // workspace layout (floats) — same 41.4M-float footprint as prior version
    float* xh    = ws;                         //  4,096,000
    float* xd    = ws + 4096000LL;             //  4,096,000
    float* xp1   = ws + 8192000LL;             // 12,288,000
    float* xp2   = ws + 20480000LL;            // 12,288,000
    float* outh  = ws + 32768000LL;            //  4,096,000
    float* outd  = ws + 36864000LL;            //  4,096,000
    float* wT1   = ws + 40960000LL;            //    196,608
    float* wT2   = ws + 41156608LL;            //    196,608
    float* cs    = ws + 41353216LL;            //      8,192
    // aliases of dead regions:
    float* quesTh = xp1;                       // 1,536,000 (dead once xp1 written)
    float* quesTd = ws + 9728000LL;            // 1,536,000
    float* attn   = xp1;                       // 8,000,000 (xp1 dead after GRU)
    float* ens    = xp2;                       // 8,192,000 (xp2 dead after GRU)
    float* tmp    = ws + 28672000LL;           // 4,096,000 (tail of xp2)
    float* outhT  = ws;                        // 4,096,000 (xh dead after projections)
    float* outdT  = ws + 4096000LL;            // 4,096,000 (xd dead)

    float* out_c = (float*)d_out;              // [16000,3000]
    float* out_t = out_c + 48000000LL;
    float* out_e = out_c + 96000000LL;

    const dim3 blk(256);

    // 0) transpose ques tables to [EMB, 2NQ] (K-major for MFMA B-operand)
    trans_kernel<<<dim3(8, 188, 1), blk, 0, stream>>>(ques_h, quesTh, X_K, EMB, 0, 0);
    trans_kernel<<<dim3(8, 188, 1), blk, 0, stream>>>(ques_d, quesTd, X_K, EMB, 0, 0);

    // 1) embeddings: xh = x @ quesTh^T, xd = x @ quesTd^T   [16000,6000]x[256,6000]^T
    gemm_mfma<false><<<dim3(2, 125, 1), blk, 0, stream>>>(
        x, quesTh, nullptr, xh, ROWS, EMB, X_K, EMB, 0, 0, 0);
    gemm_mfma<false><<<dim3(2, 125, 1), blk, 0, stream>>>(
        x, quesTd, nullptr, xd, ROWS, EMB, X_K, EMB, 0, 0, 0);

    // 2) input projections: xp = xemb @ w_ih^T + b_ih   [16000,256]x[768,256]^T
    gemm_mfma<true><<<dim3(6, 125, 1), blk, 0, stream>>>(
        xh, w1ih, b1ih, xp1, ROWS, 768, EMB, 768, 0, 0, 0);
    gemm_mfma<true><<<dim3(6, 125, 1), blk, 0, stream>>>(
        xd, w2ih, b2ih, xp2, ROWS, 768, EMB, 768, 0, 0, 0);

    // 3) transpose recurrent weights for the GRU's coalesced access
    trans_kernel<<<dim3(8, 24, 1), blk, 0, stream>>>(w1hh, wT1, 768, 256, 0, 0);
    trans_kernel<<<dim3(8, 24, 1), blk, 0, stream>>>(w2hh, wT2, 768, 256, 0, 0);

    // 4) dual GRU, one block per (gru,batch)
    gru_kernel<<<64, blk, 0, stream>>>(xp1, xp2, wT1, wT2, b1hh, b2hh, outh, outd);

    // 5) per-branch logits  [16000,256]x[3000,256]^T
    gemm_mfma<true><<<dim3(24, 125, 1), blk, 0, stream>>>(
        outh, fcc_w, fcc_b, out_c, ROWS, NQ, HID, NQ, 0, 0, 0);
    gemm_mfma<true><<<dim3(24, 125, 1), blk, 0, stream>>>(
        outd, fct_w, fct_b, out_t, ROWS, NQ, HID, NQ, 0, 0, 0);

    // 6) batched transposes of GRU outputs: [500,256] -> [256,500] per batch
    trans_kernel<<<dim3(8, 16, 32), blk, 0, stream>>>(outh, outhT, SEQ, HID, 128000, 128000);
    trans_kernel<<<dim3(8, 16, 32), blk, 0, stream>>>(outd, outdT, SEQ, HID, 128000, 128000);

    // 7) attention scores: scores[b] = outh[b] @ outd[b]^T   [500,256]x[500,256]^T
    gemm_mfma<false><<<dim3(4, 4, 32), blk, 0, stream>>>(
        outh, outd, nullptr, attn, SEQ, SEQ, HID, SEQ,
        (long long)SEQ * HID, (long long)SEQ * HID, (long long)SEQ * SEQ);

    // 8) softmax rows (in place)
    softmax_kernel<<<ROWS, blk, 0, stream>>>(attn);

    // 9) colsum of outh per batch (for the 1-attn trick)
    colsum_kernel<<<32, blk, 0, stream>>>(outh, cs);

    // 10) fused_d = attn @ outd -> ens[:,0:256]; tmp = attn @ outh
    //     A = attn [500,500] (lda=500), B = out*T [256,500] (ldb=500)
    gemm_mfma<false><<<dim3(2, 4, 32), blk, 0, stream>>>(
        attn, outdT, nullptr, ens, SEQ, HID, SEQ, 512,
        (long long)SEQ * SEQ, (long long)HID * SEQ, (long long)SEQ * 512);
    gemm_mfma<false><<<dim3(2, 4, 32), blk, 0, stream>>>(
        attn, outhT, nullptr, tmp, SEQ, HID, SEQ, HID,
        (long long)SEQ * SEQ, (long long)HID * SEQ, (long long)SEQ * HID);

    // 11) ens[:,256:512] = colsum - tmp
    combine_kernel<<<ROWS, blk, 0, stream>>>(tmp, cs, ens);

    // 12) ensemble logits: out_e = ens @ fce_w^T + fce_b   [16000,512]x[3000,512]^T
    gemm_mfma<true><<<dim3(24, 125, 1), blk, 0, stream>>>(
        ens, fce_w, fce_b, out_e, ROWS, NQ, 512, NQ, 0, 0, 0);
}